// Round 11
// baseline (7982.728 us; speedup 1.0000x reference)
//
#include <hip/hip_runtime.h>
#include <math.h>

#define Bn   32
#define Cn   512
#define HIDn 32
#define BCn  (Bn*Cn)
#define PPBLK 4              // planes per block (1 per wave)
#define NBLK  (BCn/PPBLK)    // 4096 blocks
#define BPB   128            // blocks per batch (512 planes / 4)

typedef float f32x4 __attribute__((ext_vector_type(4)));

__global__ void zero_flags(int* __restrict__ p) { p[threadIdx.x] = 0; }

// ---------------------------------------------------------------------------
// Single fused persistent-dependency kernel. Block i owns planes [4i,4i+4)
// (one per wave, held in r[16] registers end-to-end — x is read from HBM
// exactly once). Batch b = i>>7 (128 blocks per batch).
//
// Stats: proven R9 wave butterfly; lane0 writes the 4 quadrant avgs+maxes.
// Region-0 (global) stats are derived by the producer from quadrants
// (mean-of-means / max-of-maxes — exact).
//
// Producer election: last arriver (atomicAdd(counter[b]) == 127) computes
// the MLP for its batch — it has proof all stats are written, so it never
// waits: deadlock-free regardless of dispatch order. Everyone else
// acquire-spins on flag[b] (tid0 only, s_sleep-throttled), then applies.
// ---------------------------------------------------------------------------
__global__ __launch_bounds__(256) void fused_kernel(
    const float* __restrict__ x,
    const float* __restrict__ Wa1, const float* __restrict__ ba1,
    const float* __restrict__ Wa2, const float* __restrict__ ba2,
    const float* __restrict__ Wm1, const float* __restrict__ bm1,
    const float* __restrict__ Wm2, const float* __restrict__ bm2,
    const float* __restrict__ fusion_w,
    float* __restrict__ avg_q, float* __restrict__ max_q,
    float* __restrict__ scale_ws,
    int* __restrict__ counters, int* __restrict__ flags,
    float* __restrict__ out) {
  const int tid  = threadIdx.x;
  const int wv   = tid >> 6;
  const int lane = tid & 63;
  const int plane = blockIdx.x * PPBLK + wv;     // b*Cn + c
  const int b     = blockIdx.x >> 7;             // batch

  // ---------------- phase 1: load plane into regs + quadrant stats --------
  const f32x4* xp = (const f32x4*)(x + (size_t)plane * 4096);
  f32x4 r[16];
  float sT = 0.f, sB = 0.f, mT = -INFINITY, mB = -INFINITY;
#pragma unroll
  for (int i = 0; i < 16; ++i) {
    f32x4 v = xp[lane + 64 * i];
    r[i] = v;
    float s = (v.x + v.y) + (v.z + v.w);
    float m = fmaxf(fmaxf(v.x, v.y), fmaxf(v.z, v.w));
    if (i < 8) { sT += s; mT = fmaxf(mT, m); }
    else       { sB += s; mB = fmaxf(mB, m); }
  }
  const int masks[5] = {1, 2, 4, 16, 32};
#pragma unroll
  for (int t = 0; t < 5; ++t) {
    const int msk = masks[t];
    sT += __shfl_xor(sT, msk);
    sB += __shfl_xor(sB, msk);
    mT = fmaxf(mT, __shfl_xor(mT, msk));
    mB = fmaxf(mB, __shfl_xor(mB, msk));
  }
  const float sTo = __shfl_xor(sT, 8), sBo = __shfl_xor(sB, 8);
  const float mTo = __shfl_xor(mT, 8), mBo = __shfl_xor(mB, 8);

  if (lane == 0) {   // quadrant order: (0,0),(0,1),(1,0),(1,1)
    avg_q[0 * BCn + plane] = sT  * (1.f / 1024.f);
    avg_q[1 * BCn + plane] = sTo * (1.f / 1024.f);
    avg_q[2 * BCn + plane] = sB  * (1.f / 1024.f);
    avg_q[3 * BCn + plane] = sBo * (1.f / 1024.f);
    max_q[0 * BCn + plane] = mT;
    max_q[1 * BCn + plane] = mTo;
    max_q[2 * BCn + plane] = mB;
    max_q[3 * BCn + plane] = mBo;
  }

  // ---------------- phase 2: last arriver computes the batch MLP -----------
  __shared__ int s_last;
  __syncthreads();   // all stats stores drained (vmcnt) before the release add
  if (tid == 0)
    s_last = (__hip_atomic_fetch_add(&counters[b], 1, __ATOMIC_ACQ_REL,
                                     __HIP_MEMORY_SCOPE_AGENT) == BPB - 1);
  __syncthreads();

  if (s_last) {
    __shared__ float s_h[2][5][HIDn];
    // layer 1: 2 mlps x 5 regions x 32 hidden dots of length 512
    for (int d = tid; d < 320; d += 256) {
      const int m = d / 160, rr = d % 160;
      const int s = rr >> 5, k = rr & 31;
      const float* W1 = m ? Wm1 : Wa1;
      const float* b1 = m ? bm1 : ba1;
      const float* qb = (m ? max_q : avg_q) + b * Cn;   // + q*BCn + c
      float acc = b1[k];
      for (int c = 0; c < Cn; ++c) {
        float v;
        if (s == 0) {   // global region derived from quadrants
          const float q1 = qb[0 * BCn + c], q2 = qb[1 * BCn + c];
          const float q3 = qb[2 * BCn + c], q4 = qb[3 * BCn + c];
          v = m ? fmaxf(fmaxf(q1, q2), fmaxf(q3, q4))
                : 0.25f * ((q1 + q2) + (q3 + q4));
        } else {
          v = qb[(s - 1) * BCn + c];
        }
        acc += W1[k * Cn + c] * v;
      }
      s_h[m][s][k] = fmaxf(acc, 0.f);
    }
    __syncthreads();

    // fusion softmax (uniform) + layer 2 + sigmoids -> scale_ws
    float fw[5]; float fmx = -INFINITY;
#pragma unroll
    for (int s = 0; s < 5; ++s) { fw[s] = fusion_w[s]; fmx = fmaxf(fmx, fw[s]); }
    float fsum = 0.f;
#pragma unroll
    for (int s = 0; s < 5; ++s) { fw[s] = expf(fw[s] - fmx); fsum += fw[s]; }
    const float finv = 1.f / fsum;

    for (int c = tid; c < Cn; c += 256) {
      const float* wa = Wa2 + c * HIDn;
      const float* wm = Wm2 + c * HIDn;
      const float bias = ba2[c] + bm2[c];
      float f[5];
#pragma unroll
      for (int s = 0; s < 5; ++s) {
        float acc = bias;
#pragma unroll
        for (int k = 0; k < HIDn; ++k)
          acc += wa[k] * s_h[0][s][k] + wm[k] * s_h[1][s][k];
        f[s] = acc;
      }
      float fused = 0.f;
#pragma unroll
      for (int s = 0; s < 5; ++s) fused += fw[s] * f[s];
      fused *= finv;
      const float g = 1.f / (1.f + expf(-fused));
      f32x4 sc;
      sc.x = 1.f / (1.f + expf(-f[1])) + g;   // (0,0)
      sc.y = 1.f / (1.f + expf(-f[2])) + g;   // (0,1)
      sc.z = 1.f / (1.f + expf(-f[3])) + g;   // (1,0)
      sc.w = 1.f / (1.f + expf(-f[4])) + g;   // (1,1)
      ((f32x4*)scale_ws)[b * Cn + c] = sc;
    }
    __syncthreads();   // all scale stores drained
    if (tid == 0) {
      __threadfence();
      __hip_atomic_store(&flags[b], 1, __ATOMIC_RELEASE,
                         __HIP_MEMORY_SCOPE_AGENT);
    }
  }

  // ---------------- phase 3: wait for scales, apply from registers ---------
  if (tid == 0) {
    while (__hip_atomic_load(&flags[b], __ATOMIC_ACQUIRE,
                             __HIP_MEMORY_SCOPE_AGENT) == 0)
      __builtin_amdgcn_s_sleep(8);
  }
  __syncthreads();   // tid0's acquire happens-before everyone's scale read

  const int jside = ((lane & 15) >= 8) ? 1 : 0;
  const f32x4 sc = ((const f32x4*)scale_ws)[plane];
  const float scT = jside ? sc.y : sc.x;
  const float scB = jside ? sc.w : sc.z;

  f32x4* op = (f32x4*)(out + (size_t)plane * 4096);
#pragma unroll
  for (int i = 0; i < 16; ++i) {
    f32x4 v = r[i] * ((i < 8) ? scT : scB);
    __builtin_nontemporal_store(v, &op[lane + 64 * i]);
  }
}

extern "C" void kernel_launch(void* const* d_in, const int* in_sizes, int n_in,
                              void* d_out, int out_size, void* d_ws, size_t ws_size,
                              hipStream_t stream) {
  const float* x        = (const float*)d_in[0];
  const float* Wa1      = (const float*)d_in[1];
  const float* ba1      = (const float*)d_in[2];
  const float* Wa2      = (const float*)d_in[3];
  const float* ba2      = (const float*)d_in[4];
  const float* Wm1      = (const float*)d_in[5];
  const float* bm1      = (const float*)d_in[6];
  const float* Wm2      = (const float*)d_in[7];
  const float* bm2      = (const float*)d_in[8];
  const float* fusion_w = (const float*)d_in[9];
  float* out = (float*)d_out;

  float* ws       = (float*)d_ws;
  float* avg_q    = ws;                   // [4][B*C]
  float* max_q    = ws + 4 * BCn;         // [4][B*C]
  float* scale_ws = ws + 8 * BCn;         // [B*C][4]
  int*   counters = (int*)(ws + 12 * BCn); // [32]
  int*   flags    = counters + 32;         // [32]

  zero_flags<<<1, 64, 0, stream>>>(counters);   // zero counters+flags each call
  fused_kernel<<<NBLK, 256, 0, stream>>>(x,
                                         Wa1, ba1, Wa2, ba2,
                                         Wm1, bm1, Wm2, bm2,
                                         fusion_w,
                                         avg_q, max_q, scale_ws,
                                         counters, flags, out);
}

// Round 12
// 157.418 us; speedup vs baseline: 50.7104x; 50.7104x over previous
//
#include <hip/hip_runtime.h>
#include <math.h>

#define Bn  32
#define Cn  512
#define HIDn 32
#define BCn (Bn*Cn)

typedef float f32x4 __attribute__((ext_vector_type(4)));

// ---------------------------------------------------------------------------
// Kernel 1: quadrant/global stats, ONE WAVE PER PLANE (no LDS, no barriers).
// Lane l reads f4 indices l + 64*i (i=0..15): row = (l>>4)+4*i, col4 = l&15.
// i<8 <=> top half; (l&15)<8 <=> left half. Butterfly masks 1,2,4 reduce the
// j-octet, 16,32 combine row-groups; xor-8 fetches the other column side.
// Measured ~35 us (~7.6 TB/s read) — at floor.
// ---------------------------------------------------------------------------
__global__ __launch_bounds__(256) void stats_kernel(const float* __restrict__ x,
                                                    float* __restrict__ avg_all,
                                                    float* __restrict__ max_all) {
  const int wave = threadIdx.x >> 6;
  const int lane = threadIdx.x & 63;
  const int plane = blockIdx.x * 4 + wave;            // b*Cn + c
  const f32x4* xp = (const f32x4*)(x + (size_t)plane * 4096);

  float sT = 0.f, sB = 0.f, mT = -INFINITY, mB = -INFINITY;
#pragma unroll
  for (int i = 0; i < 16; ++i) {
    f32x4 v = xp[lane + 64 * i];
    float s = (v.x + v.y) + (v.z + v.w);
    float m = fmaxf(fmaxf(v.x, v.y), fmaxf(v.z, v.w));
    if (i < 8) { sT += s; mT = fmaxf(mT, m); }
    else       { sB += s; mB = fmaxf(mB, m); }
  }

  const int masks[5] = {1, 2, 4, 16, 32};
#pragma unroll
  for (int t = 0; t < 5; ++t) {
    const int msk = masks[t];
    sT += __shfl_xor(sT, msk);
    sB += __shfl_xor(sB, msk);
    mT = fmaxf(mT, __shfl_xor(mT, msk));
    mB = fmaxf(mB, __shfl_xor(mB, msk));
  }
  // other column side (lane ^ 8)
  const float sTo = __shfl_xor(sT, 8), sBo = __shfl_xor(sB, 8);
  const float mTo = __shfl_xor(mT, 8), mBo = __shfl_xor(mB, 8);

  if (lane == 0) {   // lane 0 is left side: sT=top-left, sTo=top-right, ...
    avg_all[1 * BCn + plane] = sT  * (1.f / 1024.f);   // (0,0)
    avg_all[2 * BCn + plane] = sTo * (1.f / 1024.f);   // (0,1)
    avg_all[3 * BCn + plane] = sB  * (1.f / 1024.f);   // (1,0)
    avg_all[4 * BCn + plane] = sBo * (1.f / 1024.f);   // (1,1)
    avg_all[plane]           = (sT + sTo + sB + sBo) * (1.f / 4096.f);
    max_all[1 * BCn + plane] = mT;
    max_all[2 * BCn + plane] = mTo;
    max_all[3 * BCn + plane] = mB;
    max_all[4 * BCn + plane] = mBo;
    max_all[plane]           = fmaxf(fmaxf(mT, mTo), fmaxf(mB, mBo));
  }
}

// ---------------------------------------------------------------------------
// Kernel 2: per-batch tiny MLPs + fusion + sigmoid -> per-quadrant scales.
// grid = (B, 2): block (b, y) recomputes layer 1 (cheap) and owns channels
// [y*256, y*256+256) in layer 2. scale_ws layout: [b][c][4].
// ---------------------------------------------------------------------------
__global__ __launch_bounds__(256) void mlp_kernel(
    const float* __restrict__ avg_all, const float* __restrict__ max_all,
    const float* __restrict__ Wa1, const float* __restrict__ ba1,
    const float* __restrict__ Wa2, const float* __restrict__ ba2,
    const float* __restrict__ Wm1, const float* __restrict__ bm1,
    const float* __restrict__ Wm2, const float* __restrict__ bm2,
    const float* __restrict__ fusion_w, float* __restrict__ scale_ws) {
  const int b = blockIdx.x;
  const int tid = threadIdx.x;

  __shared__ __align__(16) float s_v[2][5][Cn];   // [mlp 0=avg,1=max][region][c]
  __shared__ float s_h[2][5][HIDn];

  for (int i = tid; i < 5 * Cn; i += 256) {
    int s = i >> 9, c = i & (Cn - 1);
    s_v[0][s][c] = avg_all[s * BCn + b * Cn + c];
    s_v[1][s][c] = max_all[s * BCn + b * Cn + c];
  }
  __syncthreads();

  // layer 1: 2 mlps x 5 regions x 32 hidden = 320 dots of length 512
  for (int d = tid; d < 2 * 5 * HIDn; d += 256) {
    int mlp = d / 160, r = d % 160;
    int s = r >> 5, k = r & 31;
    const float* W1 = mlp ? Wm1 : Wa1;
    const float* b1 = mlp ? bm1 : ba1;
    const f32x4* wrow = (const f32x4*)(W1 + k * Cn);
    const f32x4* v = (const f32x4*)s_v[mlp][s];
    float acc = b1[k];
    for (int c4 = 0; c4 < Cn / 4; ++c4) {
      f32x4 w = wrow[c4], xv = v[c4];
      acc += w.x * xv.x + w.y * xv.y + w.z * xv.z + w.w * xv.w;
    }
    s_h[mlp][s][k] = fmaxf(acc, 0.f);
  }
  __syncthreads();

  // softmax of fusion_w (5 elems; uniform, cheap)
  float fw[5]; float fmx = -INFINITY;
#pragma unroll
  for (int s = 0; s < 5; ++s) { fw[s] = fusion_w[s]; fmx = fmaxf(fmx, fw[s]); }
  float fsum = 0.f;
#pragma unroll
  for (int s = 0; s < 5; ++s) { fw[s] = expf(fw[s] - fmx); fsum += fw[s]; }
  const float finv = 1.f / fsum;

  // layer 2 + fusion + sigmoids: one channel per thread
  {
    const int c = blockIdx.y * 256 + tid;
    const float* wa = Wa2 + c * HIDn;
    const float* wm = Wm2 + c * HIDn;
    const float bias = ba2[c] + bm2[c];
    float f[5];
#pragma unroll
    for (int s = 0; s < 5; ++s) {
      float acc = bias;
#pragma unroll
      for (int k = 0; k < HIDn; ++k)
        acc += wa[k] * s_h[0][s][k] + wm[k] * s_h[1][s][k];
      f[s] = acc;
    }
    float fused = 0.f;
#pragma unroll
    for (int s = 0; s < 5; ++s) fused += fw[s] * f[s];
    fused *= finv;
    const float g = 1.f / (1.f + expf(-fused));
    float4 sc;
    sc.x = 1.f / (1.f + expf(-f[1])) + g;   // quadrant (0,0)
    sc.y = 1.f / (1.f + expf(-f[2])) + g;   // quadrant (0,1)
    sc.z = 1.f / (1.f + expf(-f[3])) + g;   // quadrant (1,0)
    sc.w = 1.f / (1.f + expf(-f[4])) + g;   // quadrant (1,1)
    ((float4*)scale_ws)[b * Cn + c] = sc;
  }
}

// ---------------------------------------------------------------------------
// Kernel 3: out = x * scale[quadrant], ONE WAVE PER PLANE, REVERSE plane
// order. The stats pass streamed x forward; with the L3's random-ish
// replacement (R8: 50% hits on forward re-read) the tail of x is the part
// most likely still resident — reading it first raises the hit rate
// (stack-distance trick). nt-stores keep the out stream from evicting x.
// ---------------------------------------------------------------------------
__global__ __launch_bounds__(256) void apply_kernel(const float* __restrict__ x,
                                                    const float* __restrict__ scale_ws,
                                                    float* __restrict__ out) {
  const int wave = threadIdx.x >> 6;
  const int lane = threadIdx.x & 63;
  const int pg   = gridDim.x - 1 - blockIdx.x;     // reverse traversal
  const int plane = pg * 4 + wave;                 // b*Cn + c
  const int jside = ((lane & 15) >= 8) ? 1 : 0;

  const f32x4* xp = (const f32x4*)(x + (size_t)plane * 4096);
  f32x4* op = (f32x4*)(out + (size_t)plane * 4096);

  f32x4 r[16];
#pragma unroll
  for (int i = 0; i < 16; ++i)
    r[i] = xp[lane + 64 * i];

  const float scT = scale_ws[plane * 4 + jside];       // top-left/right
  const float scB = scale_ws[plane * 4 + 2 + jside];   // bottom-left/right

#pragma unroll
  for (int i = 0; i < 16; ++i) {
    f32x4 v = r[i] * ((i < 8) ? scT : scB);
    __builtin_nontemporal_store(v, &op[lane + 64 * i]);
  }
}

extern "C" void kernel_launch(void* const* d_in, const int* in_sizes, int n_in,
                              void* d_out, int out_size, void* d_ws, size_t ws_size,
                              hipStream_t stream) {
  const float* x        = (const float*)d_in[0];
  const float* Wa1      = (const float*)d_in[1];
  const float* ba1      = (const float*)d_in[2];
  const float* Wa2      = (const float*)d_in[3];
  const float* ba2      = (const float*)d_in[4];
  const float* Wm1      = (const float*)d_in[5];
  const float* bm1      = (const float*)d_in[6];
  const float* Wm2      = (const float*)d_in[7];
  const float* bm2      = (const float*)d_in[8];
  const float* fusion_w = (const float*)d_in[9];
  float* out = (float*)d_out;

  float* ws       = (float*)d_ws;
  float* avg_all  = ws;                 // [5][B*C]
  float* max_all  = ws + 5 * BCn;       // [5][B*C]
  float* scale_ws = ws + 10 * BCn;      // [B*C][4]

  stats_kernel<<<BCn / 4, 256, 0, stream>>>(x, avg_all, max_all);
  mlp_kernel<<<dim3(Bn, 2), 256, 0, stream>>>(avg_all, max_all,
                                              Wa1, ba1, Wa2, ba2,
                                              Wm1, bm1, Wm2, bm2,
                                              fusion_w, scale_ws);
  apply_kernel<<<BCn / 4, 256, 0, stream>>>(x, scale_ws, out);
}